// Round 1
// baseline (288.286 us; speedup 1.0000x reference)
//
#include <hip/hip_runtime.h>

#define NGK   5
#define NFK   10
#define NWK   8
#define STEPW 16      // NG + NF + 1
#define NSEQ  512
#define FDIM  32
#define BIGV  1000000000.0f
#define XSTR  36      // padded LDS row stride in floats (144B, 16B-aligned, conflict-free-ish)

#if __has_builtin(__builtin_amdgcn_exp2f)
#define EXP2F(x) __builtin_amdgcn_exp2f(x)
#else
#define EXP2F(x) exp2f(x)
#endif
#if __has_builtin(__builtin_amdgcn_logf)
#define LOG2F(x) __builtin_amdgcn_logf(x)
#else
#define LOG2F(x) log2f(x)
#endif

// One block per batch element. Thread i owns DP row i.
__global__ __launch_bounds__(512, 1) void sdtw_kernel(
    const float* __restrict__ data, const int* __restrict__ lens,
    float* __restrict__ dists)
{
    __shared__ __align__(16) float LX[NSEQ * XSTR];   // 73728 B
    __shared__ float LSQ[NSEQ];                        // 2 KB
    __shared__ float RB[3][NSEQ + 2];                  // ~6 KB, slot s holds R[s-1]; slot 0 == BIG forever

    const int b = blockIdx.x;
    const int t = threadIdx.x;
    const float* xb = data + (size_t)b * (NSEQ * FDIM);

    // ---- stage x into LDS (padded layout), coalesced float4 ----
    // 512*32 floats = 4096 float4; 512 threads -> 8 each
    #pragma unroll
    for (int r = 0; r < 8; ++r) {
        int q  = r * 512 + t;          // float4 index
        int j  = q >> 3;               // row
        int c4 = (q & 7) << 2;         // float col
        float4 v = ((const float4*)xb)[q];
        *(float4*)&LX[j * XSTR + c4] = v;
    }
    // init R buffers to BIG
    for (int idx = t; idx < 3 * (NSEQ + 2); idx += 512) {
        ((float*)RB)[idx] = BIGV;
    }
    __syncthreads();

    // ---- per-thread row: x_i into registers, squared norm ----
    const int i = t;
    float4 xi[8];
    float sqi = 0.f;
    {
        const float* src = &LX[i * XSTR];
        #pragma unroll
        for (int c = 0; c < 8; ++c) {
            float4 v = *(const float4*)&src[c * 4];
            xi[c] = v;
            sqi += v.x * v.x + v.y * v.y + v.z * v.z + v.w * v.w;
        }
        LSQ[i] = sqi;
    }
    int L = lens[b];
    L = L < 1 ? 1 : (L > NSEQ ? NSEQ : L);
    __syncthreads();

    // ---- k = 0: R0[0] = D[0][0] ----
    float lastR = 0.0f;
    if (i == 0) {
        float dot = 0.f;
        #pragma unroll
        for (int c = 0; c < 8; ++c) {
            float4 v = xi[c];
            dot += v.x * v.x + v.y * v.y + v.z * v.z + v.w * v.w;
        }
        float d00 = sqi + sqi - 2.f * dot;   // ~0
        lastR = d00;
        RB[0][1] = d00;
    }
    __syncthreads();

    const float INVGL = 0.28853900817779268f;  // 1/(gamma*ln2)
    const float GLN2  = 3.46573590279972655f;  // gamma*ln2

    // rotating buffer pointers: at step k, b0 = buf[k%3] (write), b1 = R_{k-1}, b2 = R_{k-2}
    float* b0 = RB[1];
    float* b1 = RB[0];
    float* b2 = RB[2];

    const int kend = 2 * L - 2;
    for (int k = 1; k <= kend; ++k) {
        int j = k - i;
        if (j >= 0 && j < L && i < L) {
            const float* xj = &LX[j * XSTR];
            float d0 = 0.f, d1 = 0.f, d2 = 0.f, d3 = 0.f;
            #pragma unroll
            for (int c = 0; c < 8; ++c) {
                float4 v = *(const float4*)&xj[c * 4];
                d0 = fmaf(v.x, xi[c].x, d0);
                d1 = fmaf(v.y, xi[c].y, d1);
                d2 = fmaf(v.z, xi[c].z, d2);
                d3 = fmaf(v.w, xi[c].w, d3);
            }
            float dot = (d0 + d1) + (d2 + d3);
            float Dij = sqi + LSQ[j] - 2.f * dot;

            float a  = b2[i];       // R_{k-2}[i-1]
            float bb = b1[i];       // R_{k-1}[i-1]
            float cc = b1[i + 1];   // R_{k-1}[i]
            float m  = fminf(fminf(a, bb), cc);
            float e  = EXP2F((m - a) * INVGL)
                     + EXP2F((m - bb) * INVGL)
                     + EXP2F((m - cc) * INVGL);
            float r  = Dij + m - GLN2 * LOG2F(e);
            b0[i + 1] = r;
            lastR = r;
        }
        __syncthreads();
        // rotate: next b0 = old b2, next b1 = old b0, next b2 = old b1
        float* tmp = b2; b2 = b1; b1 = b0; b0 = tmp;
    }

    if (i == L - 1) {
        dists[b] = lastR / (2.0f * (float)L);
    }
}

// Tiny finalize: hard-triplet reduction over the 128 distances -> scalar
__global__ __launch_bounds__(64) void finalize_kernel(
    const float* __restrict__ dists, float* __restrict__ out)
{
    __shared__ float acc[NWK];
    const int t = threadIdx.x;
    const int g = NGK + 1;  // 6
    if (t < NWK) {
        float dd[STEPW];
        #pragma unroll
        for (int s = 0; s < STEPW; ++s) dd[s] = dists[t * STEPW + s];

        float sum_lks = 0.f, nnz = 0.f;
        for (int ii = 0; ii < g; ++ii) {
            float mx = 0.f;  // scores are relu'd (>=0), so 0 is a safe identity
            for (int jj = 0; jj < g; ++jj) {
                float dmg_ij = 0.5f * (dd[ii] + dd[jj]);
                for (int f = 0; f < NFK; ++f) {
                    float s = dmg_ij + 1.0f - 0.5f * (dd[ii] + dd[g + f]);
                    s = fmaxf(s, 0.f);
                    mx = fmaxf(mx, s);
                }
            }
            sum_lks += mx;
            nnz += (mx != 0.f) ? 1.f : 0.f;
        }
        sum_lks *= (float)(g * NFK);   // *60
        nnz     *= (float)(g * NFK);
        float lv = sum_lks / (nnz + 1.f);

        float only_pos = 0.f;
        for (int ii = 1; ii < g; ++ii)
            for (int jj = 0; jj < ii; ++jj)
                only_pos += 0.5f * (dd[ii] + dd[jj]);
        only_pos *= (0.01f / (float)NGK);  // MODEL_LAMBDA / NG

        acc[t] = lv + only_pos;
    }
    __syncthreads();
    if (t == 0) {
        float s = 0.f;
        #pragma unroll
        for (int w = 0; w < NWK; ++w) s += acc[w];
        out[0] = s * (1.0f / (float)NWK);
    }
}

extern "C" void kernel_launch(void* const* d_in, const int* in_sizes, int n_in,
                              void* d_out, int out_size, void* d_ws, size_t ws_size,
                              hipStream_t stream)
{
    const float* data = (const float*)d_in[0];   // (128, 512, 32) f32
    const int*   lens = (const int*)d_in[1];     // (128,) i32
    float* out   = (float*)d_out;                // scalar f32
    float* dists = (float*)d_ws;                 // 128 floats scratch

    const int B = NWK * STEPW;  // 128
    sdtw_kernel<<<B, 512, 0, stream>>>(data, lens, dists);
    finalize_kernel<<<1, 64, 0, stream>>>(dists, out);
}